// Round 3
// baseline (625.747 us; speedup 1.0000x reference)
//
#include <hip/hip_runtime.h>
#include <stdint.h>

#define B_   2
#define C_   512
#define N_   4096           // 64*64 pixels
#define G_   8
#define NH_  8
#define HD_  64
#define GRPELEMS ((C_ / G_) * N_)   // 262144 per (b, group)
#define NCHUNK 16                   // partial-reduce chunks per (b, group)

typedef __bf16 bf16x8 __attribute__((ext_vector_type(8)));
typedef float  f32x4  __attribute__((ext_vector_type(4)));

#if __has_builtin(__builtin_amdgcn_exp2f)
#define EXP2(x) __builtin_amdgcn_exp2f(x)
#else
#define EXP2(x) exp2f(x)
#endif

// fp32 -> bf16 round-to-nearest-even (finite inputs only)
__device__ inline unsigned f2bf(float f) {
    union { float f; unsigned u; } v; v.f = f;
    return (v.u + 0x7FFFu + ((v.u >> 16) & 1u)) >> 16;
}
__device__ inline __bf16 tobf(float f) {
    unsigned short u = (unsigned short)f2bf(f);
    union { unsigned short u; __bf16 b; } c; c.u = u;
    return c.b;
}
// pack hi16(f1):hi16(f0) in ONE v_perm_b32 (truncation to bf16)
__device__ inline unsigned pktrunc(float f0, float f1) {
    return __builtin_amdgcn_perm(__float_as_uint(f1), __float_as_uint(f0),
                                 0x07060302u);
}
// truncate fp32 to bf16-precision fp32 (for l-sum consistency with packed P)
__device__ inline float trunc_bf(float f) {
    return __uint_as_float(__float_as_uint(f) & 0xffff0000u);
}

// async global->LDS, 16B per lane; LDS dest = wave-uniform base + lane*16
#define GLOAD16(g, l)                                                     \
    __builtin_amdgcn_global_load_lds(                                     \
        (const __attribute__((address_space(1))) unsigned*)(g),           \
        (__attribute__((address_space(3))) unsigned*)(l), 16, 0, 0)

// ---------------------------------------------------------------------------
// prep: fused GroupNorm partial stats + weight bf16 conversion.
// ---------------------------------------------------------------------------
__global__ __launch_bounds__(256) void prep(const float* __restrict__ x,
                                            const float* __restrict__ qw,
                                            const float* __restrict__ pw,
                                            float* __restrict__ psum,
                                            float* __restrict__ psq,
                                            __bf16* __restrict__ dq,
                                            __bf16* __restrict__ dp) {
    const int blk = blockIdx.x;
    const int t = threadIdx.x;
    if (blk < 256) {
        const float4* p = (const float4*)x + (size_t)blk * 4096;
        float s = 0.f, s2 = 0.f;
#pragma unroll
        for (int i = 0; i < 16; ++i) {
            float4 v = p[t + (i << 8)];
            s  += v.x + v.y + v.z + v.w;
            s2 += v.x * v.x + v.y * v.y + v.z * v.z + v.w * v.w;
        }
#pragma unroll
        for (int off = 1; off < 64; off <<= 1) {
            s  += __shfl_xor(s, off);
            s2 += __shfl_xor(s2, off);
        }
        __shared__ float rs[4], rq[4];
        if ((t & 63) == 0) { rs[t >> 6] = s; rq[t >> 6] = s2; }
        __syncthreads();
        if (t == 0) {
            psum[blk] = rs[0] + rs[1] + rs[2] + rs[3];
            psq[blk]  = rq[0] + rq[1] + rq[2] + rq[3];
        }
    } else {
        const int QW4 = (3 * C_ * C_) / 4;   // 196608 float4s
        int idx = (blk - 256) * 256 + t;
        float4 v; __bf16* dst; int o;
        if (idx < QW4) { v = ((const float4*)qw)[idx]; dst = dq; o = idx; }
        else           { v = ((const float4*)pw)[idx - QW4]; dst = dp; o = idx - QW4; }
        uint2 pk;
        pk.x = f2bf(v.x) | (f2bf(v.y) << 16);
        pk.y = f2bf(v.z) | (f2bf(v.w) << 16);
        *(uint2*)(dst + (size_t)o * 4) = pk;
    }
}

// ---------------------------------------------------------------------------
// GroupNorm finalize + apply + transpose: x[b][c][p] fp32 -> xnT[b][p][c] bf16.
// ---------------------------------------------------------------------------
__global__ __launch_bounds__(256) void gn_apply_t(const float* __restrict__ x,
                                                  const float* __restrict__ w,
                                                  const float* __restrict__ bb,
                                                  const float* __restrict__ psum,
                                                  const float* __restrict__ psq,
                                                  __bf16* __restrict__ xnT) {
    const int p0 = blockIdx.x << 6, c0 = blockIdx.y << 6, b = blockIdx.z;
    __shared__ __bf16 T[64][76];   // row stride 152 B
    __shared__ float red[2 * NCHUNK];
    __shared__ float smr[2];
    const int tid = threadIdx.x;
    const int bg = b * G_ + (c0 >> 6);

    if (tid < NCHUNK)            red[tid] = psum[bg * NCHUNK + tid];
    else if (tid < 2 * NCHUNK)   red[tid] = psq[bg * NCHUNK + tid - NCHUNK];
    __syncthreads();
    if (tid == 0) {
        float s = 0.f, q = 0.f;
#pragma unroll
        for (int i = 0; i < NCHUNK; ++i) { s += red[i]; q += red[NCHUNK + i]; }
        const float inv = 1.f / (float)GRPELEMS;
        float mean = s * inv;
        float var  = q * inv - mean * mean;
        smr[0] = mean;
        smr[1] = rsqrtf(var + 1e-5f);
    }
    __syncthreads();
    const float mean = smr[0], rstd = smr[1];

    const int tr  = tid >> 4;
    const int tc4 = (tid & 15) << 2;
    const float* xb = x + ((size_t)b * C_ + c0) * N_ + p0;
#pragma unroll
    for (int cc = tr; cc < 64; cc += 16) {
        int c = c0 + cc;
        float sc = rstd * w[c];
        float sh = bb[c] - mean * sc;
        float4 v = *(const float4*)(xb + (size_t)cc * N_ + tc4);
        T[tc4 + 0][cc] = tobf(v.x * sc + sh);
        T[tc4 + 1][cc] = tobf(v.y * sc + sh);
        T[tc4 + 2][cc] = tobf(v.z * sc + sh);
        T[tc4 + 3][cc] = tobf(v.w * sc + sh);
    }
    __syncthreads();
    __bf16* dst = xnT + ((size_t)b * N_ + p0) * C_ + c0;
#pragma unroll
    for (int pp = tr; pp < 64; pp += 16)
        *(uint2*)(dst + (size_t)pp * C_ + tc4) = *(const uint2*)&T[pp][tc4];
}

// ---------------------------------------------------------------------------
// bf16 MFMA GEMM, 64x128 tile (was 128x128): A-tile 8 KB + B-tile 16 KB,
// 4 waves in 2x2, each wave 2x4 16x16x32 microtiles. Smaller M-tile doubles
// the block count (qkv 1536 = 6/CU, proj 512 = 2/CU) so barrier drains in
// the short 8-iter K-loop overlap with co-resident blocks (m114 mechanism).
// EPI 0 epilogue writes attention operand layouts (r8-verified):
//   q: qT[bh][p][d] (pre-scaled)   k: K'[bh][d>>3][key][8]
//   v: V'[bh][key>>3][d][8]
// ---------------------------------------------------------------------------
template <int M_TOTAL, int EPI>
__global__ __launch_bounds__(256) void gemm_bf16(const __bf16* __restrict__ A,
                                                 const __bf16* __restrict__ Bm,
                                                 const float* __restrict__ bias,
                                                 const float* __restrict__ resid,
                                                 __bf16* __restrict__ qT,
                                                 __bf16* __restrict__ kP,
                                                 __bf16* __restrict__ vP,
                                                 float* __restrict__ Y) {
    const int b  = blockIdx.z;
    const int M0 = blockIdx.y << 6;        // 64-row tile
    const int N0 = blockIdx.x << 7;        // 128-col tile
    const int tid = threadIdx.x;
    const int w = tid >> 6, lane = tid & 63;
    const int quad = lane >> 4, l16 = lane & 15;
    const int wr = w >> 1, wc = w & 1;

    __shared__ __bf16 As[64 * 64];    // [m][k], XOR-swizzled granules, 8 KB
    __shared__ __bf16 Bs[128 * 64];   // [n][k], 16 KB

    const __bf16* Bb = Bm + (size_t)b * ((size_t)N_ * C_);

    const int srow = lane >> 3;
    const int sg   = lane & 7;

    f32x4 acc[2][4];
#pragma unroll
    for (int mt = 0; mt < 2; ++mt)
#pragma unroll
        for (int nt = 0; nt < 4; ++nt) acc[mt][nt] = (f32x4){0.f, 0.f, 0.f, 0.f};

    for (int k0 = 0; k0 < C_; k0 += 64) {
        __syncthreads();
#pragma unroll
        for (int i = 0; i < 2; ++i) {   // A: 64 rows, 2 groups/wave
            int r  = (w << 4) + (i << 3) + srow;
            int gc = ((sg ^ (r & 7)) << 3);
            GLOAD16(A + (size_t)(M0 + r) * C_ + k0 + gc, As + (((w << 1) + i) << 9));
        }
#pragma unroll
        for (int i = 0; i < 4; ++i) {   // B: 128 rows, 4 groups/wave
            int r  = (w << 5) + (i << 3) + srow;
            int gc = ((sg ^ (r & 7)) << 3);
            GLOAD16(Bb + (size_t)(N0 + r) * C_ + k0 + gc, Bs + (((w << 2) + i) << 9));
        }
        __syncthreads();

#pragma unroll
        for (int kk = 0; kk < 2; ++kk) {
            bf16x8 af[2], bfr[4];
            const int gk = (kk << 2) + quad;
#pragma unroll
            for (int mt = 0; mt < 2; ++mt) {
                int m = (wr << 5) + (mt << 4) + l16;
                af[mt] = *(const bf16x8*)&As[(m << 6) + ((gk ^ (m & 7)) << 3)];
            }
#pragma unroll
            for (int nt = 0; nt < 4; ++nt) {
                int n = (wc << 6) + (nt << 4) + l16;
                bfr[nt] = *(const bf16x8*)&Bs[(n << 6) + ((gk ^ (n & 7)) << 3)];
            }
#pragma unroll
            for (int mt = 0; mt < 2; ++mt)
#pragma unroll
                for (int nt = 0; nt < 4; ++nt)
                    acc[mt][nt] = __builtin_amdgcn_mfma_f32_16x16x32_bf16(
                        af[mt], bfr[nt], acc[mt][nt], 0, 0, 0);
        }
    }

    if (EPI == 0) {
        const int t = M0 >> 9;
        const float sc = (t == 0) ? (0.125f * 1.44269504f) : 1.f;
#pragma unroll
        for (int mt = 0; mt < 2; ++mt) {
            const int o0 = M0 + (wr << 5) + (mt << 4) + (quad << 2);
            const int h  = (o0 >> 6) & 7;
            const int d0 = o0 & 63;
            const size_t bh = (size_t)b * NH_ + h;
            float bi[4];
#pragma unroll
            for (int r = 0; r < 4; ++r) bi[r] = bias[o0 + r];
            if (t == 0) {
                __bf16* dst = qT + (bh * N_) * HD_ + d0;
#pragma unroll
                for (int nt = 0; nt < 4; ++nt) {
                    int p = N0 + (wc << 6) + (nt << 4) + l16;
                    f32x4 v = acc[mt][nt];
                    uint2 pk;
                    pk.x = f2bf((v[0] + bi[0]) * sc) | (f2bf((v[1] + bi[1]) * sc) << 16);
                    pk.y = f2bf((v[2] + bi[2]) * sc) | (f2bf((v[3] + bi[3]) * sc) << 16);
                    *(uint2*)(dst + (size_t)p * HD_) = pk;
                }
            } else if (t == 1) {
                // K'[d0>>3][key][8]; d0&7 in {0,4}
                __bf16* dst = kP + bh * ((size_t)N_ * HD_);
                const size_t kkbase = (size_t)(d0 >> 3) * N_;
                const int rem = d0 & 7;
#pragma unroll
                for (int nt = 0; nt < 4; ++nt) {
                    int p = N0 + (wc << 6) + (nt << 4) + l16;
                    f32x4 v = acc[mt][nt];
                    uint2 pk;
                    pk.x = f2bf(v[0] + bi[0]) | (f2bf(v[1] + bi[1]) << 16);
                    pk.y = f2bf(v[2] + bi[2]) | (f2bf(v[3] + bi[3]) << 16);
                    *(uint2*)(dst + (kkbase + p) * 8 + rem) = pk;
                }
            } else {
                // V'[p>>3][d][8]
                __bf16* dst = vP + bh * ((size_t)HD_ * N_);
#pragma unroll
                for (int nt = 0; nt < 4; ++nt) {
                    int p = N0 + (wc << 6) + (nt << 4) + l16;
                    const size_t gb2 = ((size_t)(p >> 3) * HD_) * 8 + (p & 7);
                    f32x4 v = acc[mt][nt];
#pragma unroll
                    for (int r = 0; r < 4; ++r)
                        dst[gb2 + (size_t)(d0 + r) * 8] = tobf(v[r] + bi[r]);
                }
            }
        }
    } else {
#pragma unroll
        for (int mt = 0; mt < 2; ++mt) {
            const int o0 = M0 + (wr << 5) + (mt << 4) + (quad << 2);
            float bi[4];
#pragma unroll
            for (int r = 0; r < 4; ++r) bi[r] = bias[o0 + r];
#pragma unroll
            for (int nt = 0; nt < 4; ++nt) {
                int p = N0 + (wc << 6) + (nt << 4) + l16;
                f32x4 v = acc[mt][nt];
#pragma unroll
                for (int r = 0; r < 4; ++r) {
                    size_t off = ((size_t)b * C_ + o0 + r) * N_ + p;
                    Y[off] = v[r] + bi[r] + resid[off];
                }
            }
        }
    }
}

// ---------------------------------------------------------------------------
// MFMA flash attention v7: v4 loop body BYTE-IDENTICAL (the measured local
// optimum — r1/r2 proved source-level rescheduling only regresses), but
// key-split across wave pairs for 2x TLP. 8 waves/block (512 thr): pair
// p = w>>1 owns 32 q rows; half = w&1 iterates k-tiles [half*32, half*32+32).
// K/V bytes per block are unchanged (halves disjoint), so no r9-style L2
// traffic wall. Softmax has no running max (plain exp2, q pre-scaled), so
// the merge is exact: o = o0 + o1, l = l0 + l1 — one LDS exchange overlaid
// on Ps after a barrier (68-float padded rows, 2-way-free bank pattern).
// waves/SIMD 2 -> 4 fills the ~40% VALU-idle (exposed LDS round-trip + exp
// dependency) that single-wave ILP could not. __launch_bounds__(512,4) caps
// VGPR at 128 (v4 body needs 120).
// ---------------------------------------------------------------------------
__global__ __launch_bounds__(512, 4) void attn_mfma(const __bf16* __restrict__ qT,
                                                    const __bf16* __restrict__ kP,
                                                    const __bf16* __restrict__ vP,
                                                    __bf16* __restrict__ attT) {
    const int tid  = threadIdx.x;
    const int w    = tid >> 6;
    const int lane = tid & 63;
    const int quad = lane >> 4;
    const int l16  = lane & 15;
    const int l7   = l16 & 7;
    const int h = blockIdx.y, b = blockIdx.z;
    const int p    = w >> 1;                        // pair index 0..3
    const int half = w & 1;                         // key-half
    const int qw0 = (blockIdx.x << 7) + (p << 5);   // 32 q per pair

    // Ps (8 waves x 4 KB = 32 KB) overlaid by the merge buffers (35.3 KB)
    __shared__ __align__(16) float smemf[4 * 32 * 68 + 4 * 2 * 16];
    __bf16 (*Ps)[32][64] = (__bf16(*)[32][64])smemf;

    const size_t bh = (size_t)b * NH_ + h;
    const __bf16* qTb = qT + bh * ((size_t)N_ * HD_);
    const __bf16* kPb = kP + bh * ((size_t)N_ * HD_);
    const __bf16* vPb = vP + bh * ((size_t)HD_ * N_);

    // Q fragments: persistent across the whole k-loop (q pre-scaled)
    bf16x8 qf[2][2];
#pragma unroll
    for (int qt = 0; qt < 2; ++qt)
#pragma unroll
        for (int hh = 0; hh < 2; ++hh)
            qf[qt][hh] = *(const bf16x8*)(qTb +
                (size_t)(qw0 + (qt << 4) + l16) * HD_ + (hh << 5) + (quad << 3));

#define KADDR(hh, kt, kb) (kPb + (((size_t)((hh << 2) + quad) * N_) + (kb) + ((kt) << 4) + l16) * 8)
#define VADDR(h2, dt, kb) (vPb + (((size_t)(((kb) >> 3) + ((h2) << 2) + quad) * HD_) + ((dt) << 4) + l16) * 8)

    const f32x4 zero4 = {0.f, 0.f, 0.f, 0.f};
    f32x4 o[4][2];
#pragma unroll
    for (int dt = 0; dt < 4; ++dt) { o[dt][0] = zero4; o[dt][1] = zero4; }
    float lacc[2] = {0.f, 0.f};

    const int it0 = half << 5;   // this wave's 32 k-tiles

    // preload K fragments for first iteration of this half
    bf16x8 kf[2][4];
#pragma unroll
    for (int hh = 0; hh < 2; ++hh)
#pragma unroll
        for (int kt = 0; kt < 4; ++kt)
            kf[hh][kt] = *(const bf16x8*)KADDR(hh, kt, it0 << 6);

    for (int it = it0; it < it0 + 32; ++it) {
        const int kb = it << 6;

        // issue V loads early; consumed after S + softmax (latency hidden)
        bf16x8 vf[2][4];
#pragma unroll
        for (int h2 = 0; h2 < 2; ++h2)
#pragma unroll
            for (int dt = 0; dt < 4; ++dt)
                vf[h2][dt] = *(const bf16x8*)VADDR(h2, dt, kb);

        // S^T[key][q] = K . Q^T
        f32x4 s[4][2];
#pragma unroll
        for (int kt = 0; kt < 4; ++kt) { s[kt][0] = zero4; s[kt][1] = zero4; }
#pragma unroll
        for (int hh = 0; hh < 2; ++hh)
#pragma unroll
            for (int kt = 0; kt < 4; ++kt) {
                s[kt][0] = __builtin_amdgcn_mfma_f32_16x16x32_bf16(
                    kf[hh][kt], qf[0][hh], s[kt][0], 0, 0, 0);
                s[kt][1] = __builtin_amdgcn_mfma_f32_16x16x32_bf16(
                    kf[hh][kt], qf[1][hh], s[kt][1], 0, 0, 0);
            }

        // P = exp2(S); l += truncated P; pack to bf16 via v_perm truncation
#pragma unroll
        for (int qt = 0; qt < 2; ++qt)
#pragma unroll
            for (int kt = 0; kt < 4; ++kt) {
                f32x4 sv = s[kt][qt];
                float e0 = EXP2(sv[0]), e1 = EXP2(sv[1]);
                float e2 = EXP2(sv[2]), e3 = EXP2(sv[3]);
                lacc[qt] += (trunc_bf(e0) + trunc_bf(e1)) +
                            (trunc_bf(e2) + trunc_bf(e3));
                uint2 pk;
                pk.x = pktrunc(e0, e1);
                pk.y = pktrunc(e2, e3);
                *(uint2*)&Ps[w][(qt << 4) + l16]
                            [(((kt << 2) + quad) ^ (l7 << 1)) << 2] = pk;
            }

        // prefetch next K fragments (register double-buffer)
        if (it < it0 + 31) {
#pragma unroll
            for (int hh = 0; hh < 2; ++hh)
#pragma unroll
                for (int kt = 0; kt < 4; ++kt)
                    kf[hh][kt] = *(const bf16x8*)KADDR(hh, kt, kb + 64);
        }

        // O^T[d][q] += V^T . P^T
#pragma unroll
        for (int hh = 0; hh < 2; ++hh) {
            bf16x8 pf0 = *(const bf16x8*)&Ps[w][l16]
                          [(((hh << 3) + (quad << 1)) ^ (l7 << 1)) << 2];
            bf16x8 pf1 = *(const bf16x8*)&Ps[w][16 + l16]
                          [(((hh << 3) + (quad << 1)) ^ (l7 << 1)) << 2];
#pragma unroll
            for (int dt = 0; dt < 4; ++dt) {
                o[dt][0] = __builtin_amdgcn_mfma_f32_16x16x32_bf16(
                    vf[hh][dt], pf0, o[dt][0], 0, 0, 0);
                o[dt][1] = __builtin_amdgcn_mfma_f32_16x16x32_bf16(
                    vf[hh][dt], pf1, o[dt][1], 0, 0, 0);
            }
        }
    }

    // l: lane holds 16-key partial per qt; butterfly over lane bits 4,5
    float lq[2];
#pragma unroll
    for (int qt = 0; qt < 2; ++qt) {
        float v = lacc[qt];
        v += __shfl_xor(v, 16);
        v += __shfl_xor(v, 32);
        lq[qt] = v;
    }

    // ---- pair merge: o = o0 + o1, l = l0 + l1 (exact; no running max) ----
    float (*Om)[32][68] = (float(*)[32][68])smemf;               // 34816 B
    float (*Lm)[2][16]  = (float(*)[2][16])(smemf + 4 * 32 * 68);

    __syncthreads();   // all waves done with Ps; overlay is safe
    if (half == 1) {
#pragma unroll
        for (int qt = 0; qt < 2; ++qt)
#pragma unroll
            for (int dt = 0; dt < 4; ++dt)
                *(f32x4*)&Om[p][(qt << 4) + l16][(dt << 4) + (quad << 2)] =
                    o[dt][qt];
        if (quad == 0) { Lm[p][0][l16] = lq[0]; Lm[p][1][l16] = lq[1]; }
    }
    __syncthreads();
    if (half == 0) {
        // epilogue: attT[b][n][h*64+d] = (o0+o1)/(l0+l1), bf16 (RNE)
#pragma unroll
        for (int qt = 0; qt < 2; ++qt) {
            float inv = 1.f / (lq[qt] + Lm[p][qt][l16]);
            int n = qw0 + (qt << 4) + l16;
            __bf16* dst = attT + ((size_t)b * N_ + n) * C_ + h * HD_ + (quad << 2);
#pragma unroll
            for (int dt = 0; dt < 4; ++dt) {
                f32x4 po = *(const f32x4*)&Om[p][(qt << 4) + l16]
                                            [(dt << 4) + (quad << 2)];
                f32x4 ov = o[dt][qt];
                uint2 pk;
                pk.x = f2bf((ov[0] + po[0]) * inv) |
                       (f2bf((ov[1] + po[1]) * inv) << 16);
                pk.y = f2bf((ov[2] + po[2]) * inv) |
                       (f2bf((ov[3] + po[3]) * inv) << 16);
                *(uint2*)(dst + (dt << 4)) = pk;
            }
        }
    }
#undef KADDR
#undef VADDR
}

// ---------------------------------------------------------------------------
extern "C" void kernel_launch(void* const* d_in, const int* in_sizes, int n_in,
                              void* d_out, int out_size, void* d_ws, size_t ws_size,
                              hipStream_t stream) {
    const float* x      = (const float*)d_in[0];
    const float* norm_w = (const float*)d_in[1];
    const float* norm_b = (const float*)d_in[2];
    const float* qkv_w  = (const float*)d_in[3];
    const float* qkv_b  = (const float*)d_in[4];
    const float* proj_w = (const float*)d_in[5];
    const float* proj_b = (const float*)d_in[6];
    float* out = (float*)d_out;

    const size_t BCN = (size_t)B_ * C_ * N_;      // 4194304
    float* psum  = (float*)d_ws;                  // 256 floats
    float* psq   = psum + 256;                    // 256 floats
    __bf16* xnT  = (__bf16*)(psq + 256);          // [b][p][c]
    __bf16* qT   = xnT + BCN;                     // [bh][p][d]
    __bf16* kP   = qT + BCN;                      // K' [bh][d>>3][key][8]
    __bf16* vP   = kP + BCN;                      // V' [bh][key>>3][d][8]
    __bf16* attT = vP + BCN;                      // [b][n][c]
    __bf16* wq   = attT + BCN;                    // 1536x512
    __bf16* wp   = wq + (size_t)3 * C_ * C_;      // 512x512

    prep<<<1280, 256, 0, stream>>>(x, qkv_w, proj_w, psum, psq, wq, wp);
    gn_apply_t<<<dim3(N_ / 64, C_ / 64, B_), 256, 0, stream>>>(
        x, norm_w, norm_b, psum, psq, xnT);
    gemm_bf16<3 * C_, 0><<<dim3(N_ / 128, 3 * C_ / 64, B_), 256, 0, stream>>>(
        wq, xnT, qkv_b, nullptr, qT, kP, vP, nullptr);
    attn_mfma<<<dim3(N_ / 128, NH_, B_), 512, 0, stream>>>(qT, kP, vP, attT);
    gemm_bf16<C_, 1><<<dim3(N_ / 128, C_ / 64, B_), 256, 0, stream>>>(
        wp, attT, proj_b, x, nullptr, nullptr, nullptr, out);
}

// Round 5
// 209.875 us; speedup vs baseline: 2.9815x; 2.9815x over previous
//
#include <hip/hip_runtime.h>
#include <stdint.h>

#define B_   2
#define C_   512
#define N_   4096           // 64*64 pixels
#define G_   8
#define NH_  8
#define HD_  64
#define GRPELEMS ((C_ / G_) * N_)   // 262144 per (b, group)
#define NCHUNK 16                   // partial-reduce chunks per (b, group)

typedef __bf16 bf16x8 __attribute__((ext_vector_type(8)));
typedef float  f32x4  __attribute__((ext_vector_type(4)));

#if __has_builtin(__builtin_amdgcn_exp2f)
#define EXP2(x) __builtin_amdgcn_exp2f(x)
#else
#define EXP2(x) exp2f(x)
#endif

// fp32 -> bf16 round-to-nearest-even (finite inputs only)
__device__ inline unsigned f2bf(float f) {
    union { float f; unsigned u; } v; v.f = f;
    return (v.u + 0x7FFFu + ((v.u >> 16) & 1u)) >> 16;
}
__device__ inline __bf16 tobf(float f) {
    unsigned short u = (unsigned short)f2bf(f);
    union { unsigned short u; __bf16 b; } c; c.u = u;
    return c.b;
}
// pack hi16(f1):hi16(f0) in ONE v_perm_b32 (truncation to bf16)
__device__ inline unsigned pktrunc(float f0, float f1) {
    return __builtin_amdgcn_perm(__float_as_uint(f1), __float_as_uint(f0),
                                 0x07060302u);
}
// truncate fp32 to bf16-precision fp32 (for l-sum consistency with packed P)
__device__ inline float trunc_bf(float f) {
    return __uint_as_float(__float_as_uint(f) & 0xffff0000u);
}

// async global->LDS, 16B per lane; LDS dest = wave-uniform base + lane*16
#define GLOAD16(g, l)                                                     \
    __builtin_amdgcn_global_load_lds(                                     \
        (const __attribute__((address_space(1))) unsigned*)(g),           \
        (__attribute__((address_space(3))) unsigned*)(l), 16, 0, 0)

// ---------------------------------------------------------------------------
// prep: fused GroupNorm partial stats + weight bf16 conversion.
// ---------------------------------------------------------------------------
__global__ __launch_bounds__(256) void prep(const float* __restrict__ x,
                                            const float* __restrict__ qw,
                                            const float* __restrict__ pw,
                                            float* __restrict__ psum,
                                            float* __restrict__ psq,
                                            __bf16* __restrict__ dq,
                                            __bf16* __restrict__ dp) {
    const int blk = blockIdx.x;
    const int t = threadIdx.x;
    if (blk < 256) {
        const float4* p = (const float4*)x + (size_t)blk * 4096;
        float s = 0.f, s2 = 0.f;
#pragma unroll
        for (int i = 0; i < 16; ++i) {
            float4 v = p[t + (i << 8)];
            s  += v.x + v.y + v.z + v.w;
            s2 += v.x * v.x + v.y * v.y + v.z * v.z + v.w * v.w;
        }
#pragma unroll
        for (int off = 1; off < 64; off <<= 1) {
            s  += __shfl_xor(s, off);
            s2 += __shfl_xor(s2, off);
        }
        __shared__ float rs[4], rq[4];
        if ((t & 63) == 0) { rs[t >> 6] = s; rq[t >> 6] = s2; }
        __syncthreads();
        if (t == 0) {
            psum[blk] = rs[0] + rs[1] + rs[2] + rs[3];
            psq[blk]  = rq[0] + rq[1] + rq[2] + rq[3];
        }
    } else {
        const int QW4 = (3 * C_ * C_) / 4;   // 196608 float4s
        int idx = (blk - 256) * 256 + t;
        float4 v; __bf16* dst; int o;
        if (idx < QW4) { v = ((const float4*)qw)[idx]; dst = dq; o = idx; }
        else           { v = ((const float4*)pw)[idx - QW4]; dst = dp; o = idx - QW4; }
        uint2 pk;
        pk.x = f2bf(v.x) | (f2bf(v.y) << 16);
        pk.y = f2bf(v.z) | (f2bf(v.w) << 16);
        *(uint2*)(dst + (size_t)o * 4) = pk;
    }
}

// ---------------------------------------------------------------------------
// GroupNorm finalize + apply + transpose: x[b][c][p] fp32 -> xnT[b][p][c] bf16.
// ---------------------------------------------------------------------------
__global__ __launch_bounds__(256) void gn_apply_t(const float* __restrict__ x,
                                                  const float* __restrict__ w,
                                                  const float* __restrict__ bb,
                                                  const float* __restrict__ psum,
                                                  const float* __restrict__ psq,
                                                  __bf16* __restrict__ xnT) {
    const int p0 = blockIdx.x << 6, c0 = blockIdx.y << 6, b = blockIdx.z;
    __shared__ __bf16 T[64][76];   // row stride 152 B
    __shared__ float red[2 * NCHUNK];
    __shared__ float smr[2];
    const int tid = threadIdx.x;
    const int bg = b * G_ + (c0 >> 6);

    if (tid < NCHUNK)            red[tid] = psum[bg * NCHUNK + tid];
    else if (tid < 2 * NCHUNK)   red[tid] = psq[bg * NCHUNK + tid - NCHUNK];
    __syncthreads();
    if (tid == 0) {
        float s = 0.f, q = 0.f;
#pragma unroll
        for (int i = 0; i < NCHUNK; ++i) { s += red[i]; q += red[NCHUNK + i]; }
        const float inv = 1.f / (float)GRPELEMS;
        float mean = s * inv;
        float var  = q * inv - mean * mean;
        smr[0] = mean;
        smr[1] = rsqrtf(var + 1e-5f);
    }
    __syncthreads();
    const float mean = smr[0], rstd = smr[1];

    const int tr  = tid >> 4;
    const int tc4 = (tid & 15) << 2;
    const float* xb = x + ((size_t)b * C_ + c0) * N_ + p0;
#pragma unroll
    for (int cc = tr; cc < 64; cc += 16) {
        int c = c0 + cc;
        float sc = rstd * w[c];
        float sh = bb[c] - mean * sc;
        float4 v = *(const float4*)(xb + (size_t)cc * N_ + tc4);
        T[tc4 + 0][cc] = tobf(v.x * sc + sh);
        T[tc4 + 1][cc] = tobf(v.y * sc + sh);
        T[tc4 + 2][cc] = tobf(v.z * sc + sh);
        T[tc4 + 3][cc] = tobf(v.w * sc + sh);
    }
    __syncthreads();
    __bf16* dst = xnT + ((size_t)b * N_ + p0) * C_ + c0;
#pragma unroll
    for (int pp = tr; pp < 64; pp += 16)
        *(uint2*)(dst + (size_t)pp * C_ + tc4) = *(const uint2*)&T[pp][tc4];
}

// ---------------------------------------------------------------------------
// bf16 MFMA GEMM, 64x128 tile (was 128x128): A-tile 8 KB + B-tile 16 KB,
// 4 waves in 2x2, each wave 2x4 16x16x32 microtiles. Smaller M-tile doubles
// the block count (qkv 1536 = 6/CU, proj 512 = 2/CU) so barrier drains in
// the short 8-iter K-loop overlap with co-resident blocks (m114 mechanism).
// EPI 0 epilogue writes attention operand layouts (r8-verified):
//   q: qT[bh][p][d] (pre-scaled)   k: K'[bh][d>>3][key][8]
//   v: V'[bh][key>>3][d][8]
// ---------------------------------------------------------------------------
template <int M_TOTAL, int EPI>
__global__ __launch_bounds__(256) void gemm_bf16(const __bf16* __restrict__ A,
                                                 const __bf16* __restrict__ Bm,
                                                 const float* __restrict__ bias,
                                                 const float* __restrict__ resid,
                                                 __bf16* __restrict__ qT,
                                                 __bf16* __restrict__ kP,
                                                 __bf16* __restrict__ vP,
                                                 float* __restrict__ Y) {
    const int b  = blockIdx.z;
    const int M0 = blockIdx.y << 6;        // 64-row tile
    const int N0 = blockIdx.x << 7;        // 128-col tile
    const int tid = threadIdx.x;
    const int w = tid >> 6, lane = tid & 63;
    const int quad = lane >> 4, l16 = lane & 15;
    const int wr = w >> 1, wc = w & 1;

    __shared__ __bf16 As[64 * 64];    // [m][k], XOR-swizzled granules, 8 KB
    __shared__ __bf16 Bs[128 * 64];   // [n][k], 16 KB

    const __bf16* Bb = Bm + (size_t)b * ((size_t)N_ * C_);

    const int srow = lane >> 3;
    const int sg   = lane & 7;

    f32x4 acc[2][4];
#pragma unroll
    for (int mt = 0; mt < 2; ++mt)
#pragma unroll
        for (int nt = 0; nt < 4; ++nt) acc[mt][nt] = (f32x4){0.f, 0.f, 0.f, 0.f};

    for (int k0 = 0; k0 < C_; k0 += 64) {
        __syncthreads();
#pragma unroll
        for (int i = 0; i < 2; ++i) {   // A: 64 rows, 2 groups/wave
            int r  = (w << 4) + (i << 3) + srow;
            int gc = ((sg ^ (r & 7)) << 3);
            GLOAD16(A + (size_t)(M0 + r) * C_ + k0 + gc, As + (((w << 1) + i) << 9));
        }
#pragma unroll
        for (int i = 0; i < 4; ++i) {   // B: 128 rows, 4 groups/wave
            int r  = (w << 5) + (i << 3) + srow;
            int gc = ((sg ^ (r & 7)) << 3);
            GLOAD16(Bb + (size_t)(N0 + r) * C_ + k0 + gc, Bs + (((w << 2) + i) << 9));
        }
        __syncthreads();

#pragma unroll
        for (int kk = 0; kk < 2; ++kk) {
            bf16x8 af[2], bfr[4];
            const int gk = (kk << 2) + quad;
#pragma unroll
            for (int mt = 0; mt < 2; ++mt) {
                int m = (wr << 5) + (mt << 4) + l16;
                af[mt] = *(const bf16x8*)&As[(m << 6) + ((gk ^ (m & 7)) << 3)];
            }
#pragma unroll
            for (int nt = 0; nt < 4; ++nt) {
                int n = (wc << 6) + (nt << 4) + l16;
                bfr[nt] = *(const bf16x8*)&Bs[(n << 6) + ((gk ^ (n & 7)) << 3)];
            }
#pragma unroll
            for (int mt = 0; mt < 2; ++mt)
#pragma unroll
                for (int nt = 0; nt < 4; ++nt)
                    acc[mt][nt] = __builtin_amdgcn_mfma_f32_16x16x32_bf16(
                        af[mt], bfr[nt], acc[mt][nt], 0, 0, 0);
        }
    }

    if (EPI == 0) {
        const int t = M0 >> 9;
        const float sc = (t == 0) ? (0.125f * 1.44269504f) : 1.f;
#pragma unroll
        for (int mt = 0; mt < 2; ++mt) {
            const int o0 = M0 + (wr << 5) + (mt << 4) + (quad << 2);
            const int h  = (o0 >> 6) & 7;
            const int d0 = o0 & 63;
            const size_t bh = (size_t)b * NH_ + h;
            float bi[4];
#pragma unroll
            for (int r = 0; r < 4; ++r) bi[r] = bias[o0 + r];
            if (t == 0) {
                __bf16* dst = qT + (bh * N_) * HD_ + d0;
#pragma unroll
                for (int nt = 0; nt < 4; ++nt) {
                    int p = N0 + (wc << 6) + (nt << 4) + l16;
                    f32x4 v = acc[mt][nt];
                    uint2 pk;
                    pk.x = f2bf((v[0] + bi[0]) * sc) | (f2bf((v[1] + bi[1]) * sc) << 16);
                    pk.y = f2bf((v[2] + bi[2]) * sc) | (f2bf((v[3] + bi[3]) * sc) << 16);
                    *(uint2*)(dst + (size_t)p * HD_) = pk;
                }
            } else if (t == 1) {
                // K'[d0>>3][key][8]; d0&7 in {0,4}
                __bf16* dst = kP + bh * ((size_t)N_ * HD_);
                const size_t kkbase = (size_t)(d0 >> 3) * N_;
                const int rem = d0 & 7;
#pragma unroll
                for (int nt = 0; nt < 4; ++nt) {
                    int p = N0 + (wc << 6) + (nt << 4) + l16;
                    f32x4 v = acc[mt][nt];
                    uint2 pk;
                    pk.x = f2bf(v[0] + bi[0]) | (f2bf(v[1] + bi[1]) << 16);
                    pk.y = f2bf(v[2] + bi[2]) | (f2bf(v[3] + bi[3]) << 16);
                    *(uint2*)(dst + (kkbase + p) * 8 + rem) = pk;
                }
            } else {
                // V'[p>>3][d][8]
                __bf16* dst = vP + bh * ((size_t)HD_ * N_);
#pragma unroll
                for (int nt = 0; nt < 4; ++nt) {
                    int p = N0 + (wc << 6) + (nt << 4) + l16;
                    const size_t gb2 = ((size_t)(p >> 3) * HD_) * 8 + (p & 7);
                    f32x4 v = acc[mt][nt];
#pragma unroll
                    for (int r = 0; r < 4; ++r)
                        dst[gb2 + (size_t)(d0 + r) * 8] = tobf(v[r] + bi[r]);
                }
            }
        }
    } else {
#pragma unroll
        for (int mt = 0; mt < 2; ++mt) {
            const int o0 = M0 + (wr << 5) + (mt << 4) + (quad << 2);
            float bi[4];
#pragma unroll
            for (int r = 0; r < 4; ++r) bi[r] = bias[o0 + r];
#pragma unroll
            for (int nt = 0; nt < 4; ++nt) {
                int p = N0 + (wc << 6) + (nt << 4) + l16;
                f32x4 v = acc[mt][nt];
#pragma unroll
                for (int r = 0; r < 4; ++r) {
                    size_t off = ((size_t)b * C_ + o0 + r) * N_ + p;
                    Y[off] = v[r] + bi[r] + resid[off];
                }
            }
        }
    }
}

// ---------------------------------------------------------------------------
// MFMA flash attention v8 (resubmit — r4 bench died to container failure,
// not the kernel): key-split wave pairs (v7 structure, r3-verified CORRECT)
// with the launch-bounds bug fixed. r3's __launch_bounds__(512,4) was
// interpreted as 4 BLOCKS/CU -> 32 waves/CU -> VGPR capped at 64 -> ~120
// regs of loop state spilled to scratch (FETCH 980MB, WRITE 1.3GB, 513us).
// Fix: plain __launch_bounds__(512); allocator picks the v4 body's natural
// ~120-130 VGPR; occupancy lands at 4 waves/SIMD (2 blocks/CU), double
// v4's grid-capped 2 waves/SIMD. Loop body BYTE-IDENTICAL to v4 (measured
// local optimum — r1/r2 proved source rescheduling only regresses). Pair
// p = w>>1 owns 32 q rows; half = w&1 does k-tiles [half*32, half*32+32).
// Merge exact (no running max): o = o0+o1, l = l0+l1 via one LDS exchange
// overlaid on Ps after a barrier.
// ---------------------------------------------------------------------------
__global__ __launch_bounds__(512) void attn_mfma(const __bf16* __restrict__ qT,
                                                 const __bf16* __restrict__ kP,
                                                 const __bf16* __restrict__ vP,
                                                 __bf16* __restrict__ attT) {
    const int tid  = threadIdx.x;
    const int w    = tid >> 6;
    const int lane = tid & 63;
    const int quad = lane >> 4;
    const int l16  = lane & 15;
    const int l7   = l16 & 7;
    const int h = blockIdx.y, b = blockIdx.z;
    const int p    = w >> 1;                        // pair index 0..3
    const int half = w & 1;                         // key-half
    const int qw0 = (blockIdx.x << 7) + (p << 5);   // 32 q per pair

    // Ps (8 waves x 4 KB = 32 KB) overlaid by the merge buffers (35.3 KB)
    __shared__ __align__(16) float smemf[4 * 32 * 68 + 4 * 2 * 16];
    __bf16 (*Ps)[32][64] = (__bf16(*)[32][64])smemf;

    const size_t bh = (size_t)b * NH_ + h;
    const __bf16* qTb = qT + bh * ((size_t)N_ * HD_);
    const __bf16* kPb = kP + bh * ((size_t)N_ * HD_);
    const __bf16* vPb = vP + bh * ((size_t)HD_ * N_);

    // Q fragments: persistent across the whole k-loop (q pre-scaled)
    bf16x8 qf[2][2];
#pragma unroll
    for (int qt = 0; qt < 2; ++qt)
#pragma unroll
        for (int hh = 0; hh < 2; ++hh)
            qf[qt][hh] = *(const bf16x8*)(qTb +
                (size_t)(qw0 + (qt << 4) + l16) * HD_ + (hh << 5) + (quad << 3));

#define KADDR(hh, kt, kb) (kPb + (((size_t)((hh << 2) + quad) * N_) + (kb) + ((kt) << 4) + l16) * 8)
#define VADDR(h2, dt, kb) (vPb + (((size_t)(((kb) >> 3) + ((h2) << 2) + quad) * HD_) + ((dt) << 4) + l16) * 8)

    const f32x4 zero4 = {0.f, 0.f, 0.f, 0.f};
    f32x4 o[4][2];
#pragma unroll
    for (int dt = 0; dt < 4; ++dt) { o[dt][0] = zero4; o[dt][1] = zero4; }
    float lacc[2] = {0.f, 0.f};

    const int it0 = half << 5;   // this wave's 32 k-tiles

    // preload K fragments for first iteration of this half
    bf16x8 kf[2][4];
#pragma unroll
    for (int hh = 0; hh < 2; ++hh)
#pragma unroll
        for (int kt = 0; kt < 4; ++kt)
            kf[hh][kt] = *(const bf16x8*)KADDR(hh, kt, it0 << 6);

    for (int it = it0; it < it0 + 32; ++it) {
        const int kb = it << 6;

        // issue V loads early; consumed after S + softmax (latency hidden)
        bf16x8 vf[2][4];
#pragma unroll
        for (int h2 = 0; h2 < 2; ++h2)
#pragma unroll
            for (int dt = 0; dt < 4; ++dt)
                vf[h2][dt] = *(const bf16x8*)VADDR(h2, dt, kb);

        // S^T[key][q] = K . Q^T
        f32x4 s[4][2];
#pragma unroll
        for (int kt = 0; kt < 4; ++kt) { s[kt][0] = zero4; s[kt][1] = zero4; }
#pragma unroll
        for (int hh = 0; hh < 2; ++hh)
#pragma unroll
            for (int kt = 0; kt < 4; ++kt) {
                s[kt][0] = __builtin_amdgcn_mfma_f32_16x16x32_bf16(
                    kf[hh][kt], qf[0][hh], s[kt][0], 0, 0, 0);
                s[kt][1] = __builtin_amdgcn_mfma_f32_16x16x32_bf16(
                    kf[hh][kt], qf[1][hh], s[kt][1], 0, 0, 0);
            }

        // P = exp2(S); l += truncated P; pack to bf16 via v_perm truncation
#pragma unroll
        for (int qt = 0; qt < 2; ++qt)
#pragma unroll
            for (int kt = 0; kt < 4; ++kt) {
                f32x4 sv = s[kt][qt];
                float e0 = EXP2(sv[0]), e1 = EXP2(sv[1]);
                float e2 = EXP2(sv[2]), e3 = EXP2(sv[3]);
                lacc[qt] += (trunc_bf(e0) + trunc_bf(e1)) +
                            (trunc_bf(e2) + trunc_bf(e3));
                uint2 pk;
                pk.x = pktrunc(e0, e1);
                pk.y = pktrunc(e2, e3);
                *(uint2*)&Ps[w][(qt << 4) + l16]
                            [(((kt << 2) + quad) ^ (l7 << 1)) << 2] = pk;
            }

        // prefetch next K fragments (register double-buffer)
        if (it < it0 + 31) {
#pragma unroll
            for (int hh = 0; hh < 2; ++hh)
#pragma unroll
                for (int kt = 0; kt < 4; ++kt)
                    kf[hh][kt] = *(const bf16x8*)KADDR(hh, kt, kb + 64);
        }

        // O^T[d][q] += V^T . P^T
#pragma unroll
        for (int hh = 0; hh < 2; ++hh) {
            bf16x8 pf0 = *(const bf16x8*)&Ps[w][l16]
                          [(((hh << 3) + (quad << 1)) ^ (l7 << 1)) << 2];
            bf16x8 pf1 = *(const bf16x8*)&Ps[w][16 + l16]
                          [(((hh << 3) + (quad << 1)) ^ (l7 << 1)) << 2];
#pragma unroll
            for (int dt = 0; dt < 4; ++dt) {
                o[dt][0] = __builtin_amdgcn_mfma_f32_16x16x32_bf16(
                    vf[hh][dt], pf0, o[dt][0], 0, 0, 0);
                o[dt][1] = __builtin_amdgcn_mfma_f32_16x16x32_bf16(
                    vf[hh][dt], pf1, o[dt][1], 0, 0, 0);
            }
        }
    }

    // l: lane holds 16-key partial per qt; butterfly over lane bits 4,5
    float lq[2];
#pragma unroll
    for (int qt = 0; qt < 2; ++qt) {
        float v = lacc[qt];
        v += __shfl_xor(v, 16);
        v += __shfl_xor(v, 32);
        lq[qt] = v;
    }

    // ---- pair merge: o = o0 + o1, l = l0 + l1 (exact; no running max) ----
    float (*Om)[32][68] = (float(*)[32][68])smemf;               // 34816 B
    float (*Lm)[2][16]  = (float(*)[2][16])(smemf + 4 * 32 * 68);

    __syncthreads();   // all waves done with Ps; overlay is safe
    if (half == 1) {
#pragma unroll
        for (int qt = 0; qt < 2; ++qt)
#pragma unroll
            for (int dt = 0; dt < 4; ++dt)
                *(f32x4*)&Om[p][(qt << 4) + l16][(dt << 4) + (quad << 2)] =
                    o[dt][qt];
        if (quad == 0) { Lm[p][0][l16] = lq[0]; Lm[p][1][l16] = lq[1]; }
    }
    __syncthreads();
    if (half == 0) {
        // epilogue: attT[b][n][h*64+d] = (o0+o1)/(l0+l1), bf16 (RNE)
#pragma unroll
        for (int qt = 0; qt < 2; ++qt) {
            float inv = 1.f / (lq[qt] + Lm[p][qt][l16]);
            int n = qw0 + (qt << 4) + l16;
            __bf16* dst = attT + ((size_t)b * N_ + n) * C_ + h * HD_ + (quad << 2);
#pragma unroll
            for (int dt = 0; dt < 4; ++dt) {
                f32x4 po = *(const f32x4*)&Om[p][(qt << 4) + l16]
                                            [(dt << 4) + (quad << 2)];
                f32x4 ov = o[dt][qt];
                uint2 pk;
                pk.x = f2bf((ov[0] + po[0]) * inv) |
                       (f2bf((ov[1] + po[1]) * inv) << 16);
                pk.y = f2bf((ov[2] + po[2]) * inv) |
                       (f2bf((ov[3] + po[3]) * inv) << 16);
                *(uint2*)(dst + (dt << 4)) = pk;
            }
        }
    }
#undef KADDR
#undef VADDR
}

// ---------------------------------------------------------------------------
extern "C" void kernel_launch(void* const* d_in, const int* in_sizes, int n_in,
                              void* d_out, int out_size, void* d_ws, size_t ws_size,
                              hipStream_t stream) {
    const float* x      = (const float*)d_in[0];
    const float* norm_w = (const float*)d_in[1];
    const float* norm_b = (const float*)d_in[2];
    const float* qkv_w  = (const float*)d_in[3];
    const float* qkv_b  = (const float*)d_in[4];
    const float* proj_w = (const float*)d_in[5];
    const float* proj_b = (const float*)d_in[6];
    float* out = (float*)d_out;

    const size_t BCN = (size_t)B_ * C_ * N_;      // 4194304
    float* psum  = (float*)d_ws;                  // 256 floats
    float* psq   = psum + 256;                    // 256 floats
    __bf16* xnT  = (__bf16*)(psq + 256);          // [b][p][c]
    __bf16* qT   = xnT + BCN;                     // [bh][p][d]
    __bf16* kP   = qT + BCN;                      // K' [bh][d>>3][key][8]
    __bf16* vP   = kP + BCN;                      // V' [bh][key>>3][d][8]
    __bf16* attT = vP + BCN;                      // [b][n][c]
    __bf16* wq   = attT + BCN;                    // 1536x512
    __bf16* wp   = wq + (size_t)3 * C_ * C_;      // 512x512

    prep<<<1280, 256, 0, stream>>>(x, qkv_w, proj_w, psum, psq, wq, wp);
    gn_apply_t<<<dim3(N_ / 64, C_ / 64, B_), 256, 0, stream>>>(
        x, norm_w, norm_b, psum, psq, xnT);
    gemm_bf16<3 * C_, 0><<<dim3(N_ / 128, 3 * C_ / 64, B_), 256, 0, stream>>>(
        wq, xnT, qkv_b, nullptr, qT, kP, vP, nullptr);
    attn_mfma<<<dim3(N_ / 128, NH_, B_), 512, 0, stream>>>(qT, kP, vP, attT);
    gemm_bf16<C_, 1><<<dim3(N_ / 128, C_ / 64, B_), 256, 0, stream>>>(
        wp, attT, proj_b, x, nullptr, nullptr, nullptr, out);
}